// Round 2
// baseline (457.346 us; speedup 1.0000x reference)
//
#include <hip/hip_runtime.h>
#include <stdint.h>

#define HDIM 64
#define TDIM 512
#define WPB  4   // waves (batches) per block

// One wave (64 lanes) per batch element, f32.
// Lane i owns h[i] and W_hh row i in 16 x f32x4 registers (pinned with an
// asm anchor -- round-1 counter VGPR_Count=60 proved the compiler was NOT
// keeping the 64 weight values resident; it reloaded them in-loop).
// h[j] broadcast via LDS uniform-address reads, but all DS ops are inline
// asm with hand-counted lgkmcnt + sched_barrier(0): asm-produced values
// cannot be scalarized via v_readfirstlane (the round-1 VALU mystery:
// ~206 VALU instr/timestep instead of ~75).
// Per-wave DS ops execute in order -> h publish (ds_write) followed by
// uniform ds_read of the same row needs no barrier; LDS slices are
// wave-private.

typedef float f32x4 __attribute__((ext_vector_type(4)));

__global__ __launch_bounds__(256, 4)   // 128-VGPR cap, 4 waves/SIMD
void rnn_wave_asm(const float* __restrict__ x,
                  const float* __restrict__ W_ih,
                  const float* __restrict__ W_hh,
                  const float* __restrict__ b_ih,
                  const float* __restrict__ b_hh,
                  const float* __restrict__ fc_w,
                  const float* __restrict__ fc_b,
                  float* __restrict__ out,
                  int B)
{
    __shared__ float hbuf[WPB][HDIM];   // per-wave h broadcast row
    __shared__ float xbuf[WPB][64];     // per-wave x chunk (single buffer:
                                        // in-order DS pipe makes reuse safe)

    const int lane  = threadIdx.x & 63;
    const int wid   = threadIdx.x >> 6;
    const int batch = blockIdx.x * WPB + wid;
    if (batch >= B) return;   // wave-uniform

    // --- W_hh row `lane`: 64 f32 in 16 f32x4 regs, pinned ---
    const f32x4* wp = (const f32x4*)(W_hh + lane * HDIM);
    f32x4 w0  = wp[0],  w1  = wp[1],  w2  = wp[2],  w3  = wp[3];
    f32x4 w4  = wp[4],  w5  = wp[5],  w6  = wp[6],  w7  = wp[7];
    f32x4 w8  = wp[8],  w9  = wp[9],  w10 = wp[10], w11 = wp[11];
    f32x4 w12 = wp[12], w13 = wp[13], w14 = wp[14], w15 = wp[15];
    asm volatile("" : "+v"(w0), "+v"(w1), "+v"(w2),  "+v"(w3),
                      "+v"(w4), "+v"(w5), "+v"(w6),  "+v"(w7),
                      "+v"(w8), "+v"(w9), "+v"(w10), "+v"(w11),
                      "+v"(w12), "+v"(w13), "+v"(w14), "+v"(w15));

    const float w_ih_l = W_ih[lane];                 // I == 1
    const float bias_l = b_ih[lane] + b_hh[lane];

    const float* xb = x + (size_t)batch * TDIM;
    float h = 0.0f;

    // LDS byte addresses (generic->LDS: low 32 bits are the LDS offset)
    const uint32_t hwr  = (uint32_t)(uintptr_t)(&hbuf[wid][lane]); // per-lane
    const uint32_t hrd  = (uint32_t)(uintptr_t)(&hbuf[wid][0]);    // uniform
    const uint32_t xwr  = (uint32_t)(uintptr_t)(&xbuf[wid][lane]); // per-lane
    const uint32_t xrd0 = (uint32_t)(uintptr_t)(&xbuf[wid][0]);    // uniform

    const float TWO_LOG2E = 2.885390081777927f;      // 2*log2(e)

#define QUAD(W, Q)                     \
    a0 = fmaf(W.x, Q.x, a0);           \
    a1 = fmaf(W.y, Q.y, a1);           \
    a2 = fmaf(W.z, Q.z, a2);           \
    a3 = fmaf(W.w, Q.w, a3);

    // One timestep. XO = byte-offset string of x_t within the 32B window at xr.
    // DS issue order: hW, xR, q0-3(A), q4-7(B) -> wait(4)=[hW,xR,A done]
    //   FMA A ; issue q8-11(A') -> wait(4)=[B done] ; FMA B
    //   issue q12-15(B') -> wait(4)=[A' done] ; FMA A' ; wait(0) ; FMA B'
#define STEP(XO)                                                              \
    {                                                                         \
        asm volatile("ds_write_b32 %0, %1" :: "v"(hwr), "v"(h));              \
        int xti;                                                              \
        asm volatile("ds_read_b32 %0, %1 offset:" XO : "=v"(xti) : "v"(xr)); \
        f32x4 A0, A1, A2, A3, B0, B1, B2, B3;                                 \
        asm volatile("ds_read_b128 %0, %1 offset:0"   : "=v"(A0) : "v"(hrd));\
        asm volatile("ds_read_b128 %0, %1 offset:16"  : "=v"(A1) : "v"(hrd));\
        asm volatile("ds_read_b128 %0, %1 offset:32"  : "=v"(A2) : "v"(hrd));\
        asm volatile("ds_read_b128 %0, %1 offset:48"  : "=v"(A3) : "v"(hrd));\
        asm volatile("ds_read_b128 %0, %1 offset:64"  : "=v"(B0) : "v"(hrd));\
        asm volatile("ds_read_b128 %0, %1 offset:80"  : "=v"(B1) : "v"(hrd));\
        asm volatile("ds_read_b128 %0, %1 offset:96"  : "=v"(B2) : "v"(hrd));\
        asm volatile("ds_read_b128 %0, %1 offset:112" : "=v"(B3) : "v"(hrd));\
        asm volatile("s_waitcnt lgkmcnt(4)" ::: "memory");                    \
        __builtin_amdgcn_sched_barrier(0);                                    \
        const float xt = __builtin_bit_cast(float, xti);                      \
        float a0 = fmaf(xt, w_ih_l, bias_l);                                  \
        float a1 = 0.f, a2 = 0.f, a3 = 0.f;                                   \
        QUAD(w0, A0) QUAD(w1, A1) QUAD(w2, A2) QUAD(w3, A3)                   \
        asm volatile("ds_read_b128 %0, %1 offset:128" : "=v"(A0) : "v"(hrd));\
        asm volatile("ds_read_b128 %0, %1 offset:144" : "=v"(A1) : "v"(hrd));\
        asm volatile("ds_read_b128 %0, %1 offset:160" : "=v"(A2) : "v"(hrd));\
        asm volatile("ds_read_b128 %0, %1 offset:176" : "=v"(A3) : "v"(hrd));\
        asm volatile("s_waitcnt lgkmcnt(4)" ::: "memory");                    \
        __builtin_amdgcn_sched_barrier(0);                                    \
        QUAD(w4, B0) QUAD(w5, B1) QUAD(w6, B2) QUAD(w7, B3)                   \
        asm volatile("ds_read_b128 %0, %1 offset:192" : "=v"(B0) : "v"(hrd));\
        asm volatile("ds_read_b128 %0, %1 offset:208" : "=v"(B1) : "v"(hrd));\
        asm volatile("ds_read_b128 %0, %1 offset:224" : "=v"(B2) : "v"(hrd));\
        asm volatile("ds_read_b128 %0, %1 offset:240" : "=v"(B3) : "v"(hrd));\
        asm volatile("s_waitcnt lgkmcnt(4)" ::: "memory");                    \
        __builtin_amdgcn_sched_barrier(0);                                    \
        QUAD(w8, A0) QUAD(w9, A1) QUAD(w10, A2) QUAD(w11, A3)                 \
        asm volatile("s_waitcnt lgkmcnt(0)" ::: "memory");                    \
        __builtin_amdgcn_sched_barrier(0);                                    \
        QUAD(w12, B0) QUAD(w13, B1) QUAD(w14, B2) QUAD(w15, B3)               \
        float z = (a0 + a1) + (a2 + a3);                                      \
        float t = __builtin_amdgcn_exp2f(z * TWO_LOG2E);                      \
        float r = __builtin_amdgcn_rcpf(t + 1.0f);                            \
        h = fmaf(-2.0f, r, 1.0f);                                             \
    }

    for (int c = 0; c < TDIM / 64; ++c) {
        // stage this chunk's 64 x values (coalesced 256B global read).
        // In-order per-wave DS pipe: this write is processed after all of
        // the previous chunk's reads -> single buffer is safe.
        const float xc = xb[c * 64 + lane];
        asm volatile("ds_write_b32 %0, %1" :: "v"(xwr), "v"(xc));

        uint32_t xr = xrd0;
#pragma unroll 1
        for (int u = 0; u < 8; ++u) {
            STEP("0") STEP("4")  STEP("8")  STEP("12")
            STEP("16") STEP("20") STEP("24") STEP("28")
            xr += 32;
        }
    }
#undef STEP
#undef QUAD

    // out[batch] = sum_i h[i]*fc_w[i] + fc_b   (wave butterfly reduce)
    float v = h * fc_w[lane];
#pragma unroll
    for (int off = 32; off > 0; off >>= 1)
        v += __shfl_xor(v, off, 64);

    if (lane == 0)
        out[batch] = v + fc_b[0];
}

extern "C" void kernel_launch(void* const* d_in, const int* in_sizes, int n_in,
                              void* d_out, int out_size, void* d_ws, size_t ws_size,
                              hipStream_t stream)
{
    const float* x    = (const float*)d_in[0];
    const float* W_ih = (const float*)d_in[1];
    const float* W_hh = (const float*)d_in[2];
    const float* b_ih = (const float*)d_in[3];
    const float* b_hh = (const float*)d_in[4];
    const float* fc_w = (const float*)d_in[5];
    const float* fc_b = (const float*)d_in[6];
    float* out = (float*)d_out;

    const int B = in_sizes[0] / TDIM;          // x is (B, T, 1)
    const int blocks = (B + WPB - 1) / WPB;

    rnn_wave_asm<<<blocks, WPB * 64, 0, stream>>>(
        x, W_ih, W_hh, b_ih, b_hh, fc_w, fc_b, out, B);
}

// Round 3
// 401.620 us; speedup vs baseline: 1.1388x; 1.1388x over previous
//
#include <hip/hip_runtime.h>

#define HDIM 64
#define TDIM 512
#define WPB  4   // waves (batches) per block

// One wave (64 lanes) per batch element, f32.
// Lane i owns h[i] and W_hh row i in 16 f32x4 registers.
// h[j] broadcast to all lanes via uniform-address LDS reads (HW broadcast,
// conflict-free); x_t broadcast the same way from an LDS-staged chunk.
//
// Round-3 fix: amdgpu_waves_per_eu(4,4). The grid supplies only 4 waves/SIMD
// (4096 waves / 1024 SIMDs), but rounds 0-2 show the allocator targeting
// 8-wave occupancy (VGPR_Count 52/60/64) and spilling the 64 weight values:
// to AGPRs in r0/r1 (v_accvgpr_read tax, ~2x step cost) and to scratch in r2
// (FETCH_SIZE 4MB -> 87MB). min=max=4 waves/EU gives the allocator a
// truthful 128-VGPR budget; live set is ~108 -> weights stay resident.
// No inline asm anywhere: the compiler's own lgkmcnt staging is fine.

typedef float f32x4 __attribute__((ext_vector_type(4)));

__global__ __launch_bounds__(256)
__attribute__((amdgpu_waves_per_eu(4, 4)))
void rnn_wave_vgpr(const float* __restrict__ x,
                   const float* __restrict__ W_ih,
                   const float* __restrict__ W_hh,
                   const float* __restrict__ b_ih,
                   const float* __restrict__ b_hh,
                   const float* __restrict__ fc_w,
                   const float* __restrict__ fc_b,
                   float* __restrict__ out,
                   int B)
{
    __shared__ float hbuf[WPB][HDIM];      // per-wave h broadcast row
    __shared__ float xbuf[WPB][2][64];     // per-wave x chunk, double-buffered

    const int lane  = threadIdx.x & 63;
    const int wid   = threadIdx.x >> 6;
    const int batch = blockIdx.x * WPB + wid;
    if (batch >= B) return;   // wave-uniform

    // --- W_hh row `lane` (64 f32 = 256 B contiguous) in 16 f32x4 regs ---
    const f32x4* wp = (const f32x4*)(W_hh + lane * HDIM);
    const f32x4 w0  = wp[0],  w1  = wp[1],  w2  = wp[2],  w3  = wp[3];
    const f32x4 w4  = wp[4],  w5  = wp[5],  w6  = wp[6],  w7  = wp[7];
    const f32x4 w8  = wp[8],  w9  = wp[9],  w10 = wp[10], w11 = wp[11];
    const f32x4 w12 = wp[12], w13 = wp[13], w14 = wp[14], w15 = wp[15];

    const float w_ih_l = W_ih[lane];                 // I == 1
    const float bias_l = b_ih[lane] + b_hh[lane];

    const float* xb = x + (size_t)batch * TDIM;
    float xc = xb[lane];                             // chunk 0 of x
    float h  = 0.0f;

    float*        hrow = hbuf[wid];
    const f32x4*  hq   = (const f32x4*)hrow;

    const float TWO_LOG2E = 2.885390081777927f;      // 2*log2(e)

#define QUAD(W, q)                              \
    { f32x4 hv = hq[q];                         \
      a0 = fmaf(W.x, hv.x, a0);                 \
      a1 = fmaf(W.y, hv.y, a1);                 \
      a2 = fmaf(W.z, hv.z, a2);                 \
      a3 = fmaf(W.w, hv.w, a3); }

    for (int c = 0; c < TDIM / 64; ++c) {
        // stage this chunk's 64 x values in LDS (write buf c&1),
        // then prefetch the next chunk from global (coalesced 256B/wave)
        xbuf[wid][c & 1][lane] = xc;
        if (c + 1 < TDIM / 64)
            xc = xb[(c + 1) * 64 + lane];
        const float* xr = xbuf[wid][c & 1];

#pragma unroll 1   // keep body small; fits I$
        for (int j = 0; j < 64; ++j) {
            hrow[lane] = h;                      // ds_write_b32: publish h[i]
            float xt = xr[j];                    // ds_read_b32 broadcast (uniform addr)

            float a0 = fmaf(xt, w_ih_l, bias_l);
            float a1 = 0.f, a2 = 0.f, a3 = 0.f;
            QUAD(w0,   0)  QUAD(w1,   1)  QUAD(w2,   2)  QUAD(w3,   3)
            QUAD(w4,   4)  QUAD(w5,   5)  QUAD(w6,   6)  QUAD(w7,   7)
            QUAD(w8,   8)  QUAD(w9,   9)  QUAD(w10, 10)  QUAD(w11, 11)
            QUAD(w12, 12)  QUAD(w13, 13)  QUAD(w14, 14)  QUAD(w15, 15)
            float z = (a0 + a1) + (a2 + a3);
            // tanh(z) = 1 - 2/(1 + e^{2z}); saturates correctly for large |z|
            float t = __builtin_amdgcn_exp2f(z * TWO_LOG2E);
            float r = __builtin_amdgcn_rcpf(t + 1.0f);
            h = fmaf(-2.0f, r, 1.0f);
        }
    }
#undef QUAD

    // out[batch] = sum_i h[i]*fc_w[i] + fc_b   (wave butterfly reduce)
    float v = h * fc_w[lane];
#pragma unroll
    for (int off = 32; off > 0; off >>= 1)
        v += __shfl_xor(v, off, 64);

    if (lane == 0)
        out[batch] = v + fc_b[0];
}

extern "C" void kernel_launch(void* const* d_in, const int* in_sizes, int n_in,
                              void* d_out, int out_size, void* d_ws, size_t ws_size,
                              hipStream_t stream)
{
    const float* x    = (const float*)d_in[0];
    const float* W_ih = (const float*)d_in[1];
    const float* W_hh = (const float*)d_in[2];
    const float* b_ih = (const float*)d_in[3];
    const float* b_hh = (const float*)d_in[4];
    const float* fc_w = (const float*)d_in[5];
    const float* fc_b = (const float*)d_in[6];
    float* out = (float*)d_out;

    const int B = in_sizes[0] / TDIM;          // x is (B, T, 1)
    const int blocks = (B + WPB - 1) / WPB;

    rnn_wave_vgpr<<<blocks, WPB * 64, 0, stream>>>(
        x, W_ih, W_hh, b_ih, b_hh, fc_w, fc_b, out, B);
}

// Round 4
// 256.048 us; speedup vs baseline: 1.7862x; 1.5685x over previous
//
#include <hip/hip_runtime.h>
#include <stdint.h>

#define HDIM 64
#define TDIM 512
#define GB   16    // batches per block (one MFMA M-tile)

// ---- MFMA timestep-parallel RNN ----
// Per timestep t:  h_new[16b x 64h] = tanh( xw + h[16b x 64k] @ W_hh^T[64k x 64h] )
// Block = 4 waves; wave w owns n-slice [16w .. 16w+15] of h_new:
//   D[16x16] = A[16x32] x B[32x16]  (mfma_f32_16x16x32_f16), K=64 in 2 chunks.
// Precision: f16 hi/lo split on both h and W (3 product terms, f32 acc)
//   -> ~22-bit effective mantissa; x-projection, bias, tanh all f32.
// h ping-pongs through LDS (C-layout -> A-layout crosses lanes);
// XOR swizzle ^((row&7)<<4) keeps stride-128B A reads at the 8-way BW floor.
// One __syncthreads per step (ping-pong buffers).
//
// Fragment layouts (16x16x32, gfx950):
//   A: row m = lane&15, k = 8*(lane>>4)+e   (e = vector elem 0..7)
//   B: col n = lane&15, k = 8*(lane>>4)+e
//   C/D: col n = lane&15, row m = 4*(lane>>4)+reg   [m89-verified]

typedef float     f32x4 __attribute__((ext_vector_type(4)));
typedef _Float16  f16x8 __attribute__((ext_vector_type(8)));

__global__ __launch_bounds__(256)
__attribute__((amdgpu_waves_per_eu(1)))   // 1 wave/SIMD by grid; allow full VGPR budget
void rnn_mfma(const float* __restrict__ x,
              const float* __restrict__ W_ih,
              const float* __restrict__ W_hh,
              const float* __restrict__ b_ih,
              const float* __restrict__ b_hh,
              const float* __restrict__ fc_w,
              const float* __restrict__ fc_b,
              float* __restrict__ out,
              int B)
{
    // hh[pp][hi/lo][16 rows][64 cols] f16, byte-swizzled; 2KB per slice
    __shared__ unsigned short hh[2][2][GB * HDIM];
    __shared__ float xs[64][GB];          // x chunk, [t_local][m]
    __shared__ float red[4][GB];          // final reduction

    const int tid  = threadIdx.x;
    const int lane = tid & 63;
    const int wid  = tid >> 6;            // 0..3 : n-slice
    const int g    = lane >> 4;           // 0..3 : k-block / m-quad
    const int m16  = lane & 15;
    const int gb0  = blockIdx.x * GB;     // first batch of this block

    // ---- static per-lane data ----
    const int n = wid * 16 + m16;         // this lane's h_new column (0..63)

    // B-operand frags: W_hh^T[k][n] = W_hh[n][k]; lane needs k = 32c + 8g + e
    f16x8 Bhi[2], Blo[2];
#pragma unroll
    for (int c = 0; c < 2; ++c) {
        const float* wrow = W_hh + n * HDIM + 32 * c + 8 * g;
        const f32x4 wa = *(const f32x4*)(wrow);
        const f32x4 wb = *(const f32x4*)(wrow + 4);
#pragma unroll
        for (int e = 0; e < 4; ++e) {
            float f0 = wa[e], f1 = wb[e];
            _Float16 h0 = (_Float16)f0, h1 = (_Float16)f1;
            Bhi[c][e]     = h0;  Blo[c][e]     = (_Float16)(f0 - (float)h0);
            Bhi[c][e + 4] = h1;  Blo[c][e + 4] = (_Float16)(f1 - (float)h1);
        }
    }

    const float wih  = W_ih[n];                  // I == 1
    const float bias = b_ih[n] + b_hh[n];
    const float fcw  = fc_w[n];

    // A-frag read byte offsets (row m16, k = 32c + 8g), XOR-swizzled
    const int aoff0 = (m16 * 128 +  0 + 16 * g) ^ ((m16 & 7) << 4);
    const int aoff1 = (m16 * 128 + 64 + 16 * g) ^ ((m16 & 7) << 4);
    // h_new write byte offsets (row 4g+r, col n), same swizzle
    int woff[4];
#pragma unroll
    for (int r = 0; r < 4; ++r) {
        const int wm = 4 * g + r;
        woff[r] = (wm * 128 + 2 * n) ^ ((wm & 7) << 4);
    }

    char* const hbase = (char*)hh;

    // zero ping-pong buffer 0 (hi+lo = 4096 B): h(t=0) = 0
    ((f32x4*)hbase)[tid] = (f32x4){0.f, 0.f, 0.f, 0.f};

    // x staging indices: thread loads 4 t's of one batch row (coalesced 16B)
    const int sm = tid >> 4;              // batch row 0..15
    const int tq = tid & 15;              // t-quad

    const float TWO_LOG2E = 2.885390081777927f;   // 2*log2(e)
    float hf0 = 0.f, hf1 = 0.f, hf2 = 0.f, hf3 = 0.f;

    for (int tc = 0; tc < TDIM / 64; ++tc) {
        // stage x[gb0+sm][tc*64 + 4tq .. +3] -> xs[t_local][sm]
        const f32x4 xv4 = *(const f32x4*)(x + (size_t)(gb0 + sm) * TDIM
                                            + tc * 64 + tq * 4);
        xs[tq * 4 + 0][sm] = xv4.x;
        xs[tq * 4 + 1][sm] = xv4.y;
        xs[tq * 4 + 2][sm] = xv4.z;
        xs[tq * 4 + 3][sm] = xv4.w;
        __syncthreads();   // covers zero-init (tc==0) and xs staging

#pragma unroll 1
        for (int tj = 0; tj < 64; ++tj) {
            const int pp = tj & 1;                 // global parity: tc*64 even
            const char* rb = hbase + pp * 4096;
            char*       wb = hbase + (pp ^ 1) * 4096;

            // A frags: h[m16][k] hi/lo, two K-chunks
            const f16x8 Ahi0 = *(const f16x8*)(rb +        aoff0);
            const f16x8 Ahi1 = *(const f16x8*)(rb +        aoff1);
            const f16x8 Alo0 = *(const f16x8*)(rb + 2048 + aoff0);
            const f16x8 Alo1 = *(const f16x8*)(rb + 2048 + aoff1);

            // C init = xw: lane's 4 rows m = 4g+r get x[m,t]*wih + bias
            const f32x4 xv = *(const f32x4*)((const char*)xs + tj * 64 + 16 * g);
            f32x4 c1;
            c1.x = fmaf(xv.x, wih, bias);
            c1.y = fmaf(xv.y, wih, bias);
            c1.z = fmaf(xv.z, wih, bias);
            c1.w = fmaf(xv.w, wih, bias);
            f32x4 c2 = (f32x4){0.f, 0.f, 0.f, 0.f};
            f32x4 c3 = (f32x4){0.f, 0.f, 0.f, 0.f};

            // three 2-deep chains instead of one 6-deep (latency)
            c1 = __builtin_amdgcn_mfma_f32_16x16x32_f16(Ahi0, Bhi[0], c1, 0, 0, 0);
            c2 = __builtin_amdgcn_mfma_f32_16x16x32_f16(Ahi0, Blo[0], c2, 0, 0, 0);
            c3 = __builtin_amdgcn_mfma_f32_16x16x32_f16(Alo0, Bhi[0], c3, 0, 0, 0);
            c1 = __builtin_amdgcn_mfma_f32_16x16x32_f16(Ahi1, Bhi[1], c1, 0, 0, 0);
            c2 = __builtin_amdgcn_mfma_f32_16x16x32_f16(Ahi1, Blo[1], c2, 0, 0, 0);
            c3 = __builtin_amdgcn_mfma_f32_16x16x32_f16(Alo1, Bhi[1], c3, 0, 0, 0);

            // epilogue: tanh, split to f16 hi/lo, publish to write buffer
#pragma unroll
            for (int r = 0; r < 4; ++r) {
                const float z = c1[r] + (c2[r] + c3[r]);
                const float e = __builtin_amdgcn_exp2f(z * TWO_LOG2E);
                const float q = __builtin_amdgcn_rcpf(e + 1.0f);
                const float hv = fmaf(-2.0f, q, 1.0f);   // tanh(z)
                if (r == 0) hf0 = hv;
                if (r == 1) hf1 = hv;
                if (r == 2) hf2 = hv;
                if (r == 3) hf3 = hv;
                const _Float16 hi = (_Float16)hv;
                const _Float16 lo = (_Float16)(hv - (float)hi);
                *(_Float16*)(wb +        woff[r]) = hi;
                *(_Float16*)(wb + 2048 + woff[r]) = lo;
            }
            __syncthreads();
        }
    }

    // ---- out[b] = sum_n h[b][n] * fc_w[n] + fc_b ----
    // lane holds h (exact f32, last step) for rows m=4g+r at col n.
    float v0 = hf0 * fcw, v1 = hf1 * fcw, v2 = hf2 * fcw, v3 = hf3 * fcw;
#pragma unroll
    for (int off = 1; off < 16; off <<= 1) {     // reduce over the 16 n's in wave
        v0 += __shfl_xor(v0, off, 64);
        v1 += __shfl_xor(v1, off, 64);
        v2 += __shfl_xor(v2, off, 64);
        v3 += __shfl_xor(v3, off, 64);
    }
    if (m16 == 0) {
        red[wid][4 * g + 0] = v0;
        red[wid][4 * g + 1] = v1;
        red[wid][4 * g + 2] = v2;
        red[wid][4 * g + 3] = v3;
    }
    __syncthreads();
    if (tid < GB) {
        const float o = red[0][tid] + red[1][tid] + red[2][tid] + red[3][tid];
        out[gb0 + tid] = o + fc_b[0];
    }
}

extern "C" void kernel_launch(void* const* d_in, const int* in_sizes, int n_in,
                              void* d_out, int out_size, void* d_ws, size_t ws_size,
                              hipStream_t stream)
{
    const float* x    = (const float*)d_in[0];
    const float* W_ih = (const float*)d_in[1];
    const float* W_hh = (const float*)d_in[2];
    const float* b_ih = (const float*)d_in[3];
    const float* b_hh = (const float*)d_in[4];
    const float* fc_w = (const float*)d_in[5];
    const float* fc_b = (const float*)d_in[6];
    float* out = (float*)d_out;

    const int B = in_sizes[0] / TDIM;          // x is (B, T, 1)
    const int blocks = B / GB;                 // 256 blocks of 4 waves

    rnn_mfma<<<blocks, 256, 0, stream>>>(
        x, W_ih, W_hh, b_ih, b_hh, fc_w, fc_b, out, B);
}